// Round 10
// baseline (509.058 us; speedup 1.0000x reference)
//
#include <hip/hip_runtime.h>
#include <math.h>

// GAT 2-layer: N=50000 nodes, E=800000 edges, heads=1
// dims: 128 -> 128 (BN+ReLU) -> 112 (BN)
#define NN 50000
#define NPAD 50048               // 782 * 64, MFMA row tiles
#define NE 800000
#define NBUCK 782                // buckets of 64 dsts; 782*64 = 50048 >= NN
#define BCAP 1536                // mean 1023, sd 32 -> 16 sigma headroom
#define AGG_NBLK 2048

typedef __attribute__((ext_vector_type(8))) short bf16x8;           // MFMA A/B frag
typedef __attribute__((ext_vector_type(4))) float f32x4;            // MFMA C/D frag
typedef __attribute__((ext_vector_type(8))) unsigned short u16x8;   // 16B gather

__device__ __forceinline__ unsigned short f2bf(float x) {
    unsigned u = __float_as_uint(x);
    u += 0x7fffu + ((u >> 16) & 1);              // round-to-nearest-even
    return (unsigned short)(u >> 16);
}
__device__ __forceinline__ float bf2f(unsigned short h) {
    return __uint_as_float(((unsigned)h) << 16);
}

// ---------------- init: bcur/stats zero + ve fold + W split-transpose ----------------
// ve[0..7] = We0 @ a_edge0 ; ve[8..15] = We1 @ a_edge1   (heads=1 folding)
__global__ void k_init_cvt(int* __restrict__ bcur, float* __restrict__ stats,
                           const float* __restrict__ We0, const float* __restrict__ ae0,
                           const float* __restrict__ We1, const float* __restrict__ ae1,
                           float* __restrict__ ve,
                           const float* __restrict__ W0, const float* __restrict__ W1,
                           unsigned short* __restrict__ Wth0, unsigned short* __restrict__ Wtl0,
                           unsigned short* __restrict__ Wth1, unsigned short* __restrict__ Wtl1)
{
    int idx = blockIdx.x * 256 + threadIdx.x;
    if (idx < NBUCK) bcur[idx] = 0;
    if (idx < 512) stats[idx] = 0.f;
    if (idx < 128 * 128) {
        int k = idx / 128, c = idx % 128;
        float v = W0[idx];
        unsigned short hi = f2bf(v);
        Wth0[c * 128 + k] = hi;
        Wtl0[c * 128 + k] = f2bf(v - bf2f(hi));
    } else if (idx < 128 * 128 + 128 * 112) {
        int i2 = idx - 128 * 128;
        int k = i2 / 112, c = i2 % 112;
        float v = W1[i2];
        unsigned short hi = f2bf(v);
        Wth1[c * 128 + k] = hi;
        Wtl1[c * 128 + k] = f2bf(v - bf2f(hi));
    }
    if (blockIdx.x == gridDim.x - 1) {
        int j = threadIdx.x;
        if (j < 8) {
            float s = 0.f;
            for (int c = 0; c < 128; ++c) s += We0[j * 128 + c] * ae0[c];
            ve[j] = s;
        } else if (j < 16) {
            int jj = j - 8;
            float s = 0.f;
            for (int c = 0; c < 112; ++c) s += We1[jj * 112 + c] * ae1[c];
            ve[8 + jj] = s;
        }
    }
}

// ---------------- phase A: edge -> bucket append (line-friendly scatter) ----------------
__global__ void k_bucketA(const int* __restrict__ src, const int* __restrict__ dst,
                          const float* __restrict__ eatt, const float* __restrict__ ve,
                          int* __restrict__ bcur, int4* __restrict__ bucket)
{
    int e = blockIdx.x * 256 + threadIdx.x;
    if (e >= NE) return;
    const float4* ea = reinterpret_cast<const float4*>(eatt + (size_t)e * 8);
    float4 e0 = ea[0], e1 = ea[1];
    float a0 = e0.x * ve[0] + e0.y * ve[1] + e0.z * ve[2] + e0.w * ve[3]
             + e1.x * ve[4] + e1.y * ve[5] + e1.z * ve[6] + e1.w * ve[7];
    float a1 = e0.x * ve[8] + e0.y * ve[9] + e0.z * ve[10] + e0.w * ve[11]
             + e1.x * ve[12] + e1.y * ve[13] + e1.z * ve[14] + e1.w * ve[15];
    int d = dst[e];
    int b = d >> 6;
    int pos = atomicAdd(&bcur[b], 1);
    if (pos < BCAP) {
        int4 rec;
        rec.x = src[e];
        rec.y = __float_as_int(a0);
        rec.z = __float_as_int(a1);
        rec.w = d;
        bucket[(size_t)b * BCAP + pos] = rec;
    }
}

// ---------------- phase B: per-bucket counting sort -> pack (CSR order) + rp ----------------
__global__ void k_sortB(const int* __restrict__ bcur, const int4* __restrict__ bucket,
                        int4* __restrict__ pack, int* __restrict__ rp)
{
    __shared__ int hist[64], curloc[64];
    __shared__ int red[256];
    int b = blockIdx.x;
    int t = threadIdx.x;
    // base = sum of counts of buckets before b
    int s = 0;
    for (int i = t; i < b; i += 256) s += min(bcur[i], BCAP);
    red[t] = s;
    if (t < 64) hist[t] = 0;
    __syncthreads();
    #pragma unroll
    for (int off = 128; off > 0; off >>= 1) {
        if (t < off) red[t] += red[t + off];
        __syncthreads();
    }
    int base = red[0];
    int cnt = min(bcur[b], BCAP);
    const int4* bk = bucket + (size_t)b * BCAP;
    // pass 1: histogram by dst&63
    for (int i = t; i < cnt; i += 256)
        atomicAdd(&hist[bk[i].w & 63], 1);
    __syncthreads();
    // exclusive scan of 64 counters (single thread; 64 iters)
    if (t == 0) {
        int run = 0;
        for (int i = 0; i < 64; ++i) {
            int v = hist[i];
            hist[i] = run;
            curloc[i] = run;
            run += v;
        }
    }
    __syncthreads();
    // write rp for this bucket's dst range
    if (t < 64) {
        int d = b * 64 + t;
        if (d < NN) rp[d] = base + hist[t];
    }
    if (b == NBUCK - 1 && t == 0) rp[NN] = base + cnt;
    // pass 2: place records (block-local 16KB write window)
    for (int i = t; i < cnt; i += 256) {
        int4 r = bk[i];
        int off2 = atomicAdd(&curloc[r.w & 63], 1);
        pack[base + off2] = r;
    }
}

// ---------------- MFMA GEMM: one wave = 16 rows x COLS, bf16x3 split precision ----------------
template<int COLS, bool BN_IN>
__global__ void k_gemm_mfma(const float* __restrict__ A,
                            const unsigned short* __restrict__ Wth,
                            const unsigned short* __restrict__ Wtl,
                            unsigned short* __restrict__ out,
                            const float* __restrict__ a_src, const float* __restrict__ a_dst,
                            float* __restrict__ als, float* __restrict__ ald,
                            const float* __restrict__ bsum, const float* __restrict__ bsq,
                            const float* __restrict__ gamma, const float* __restrict__ beta)
{
    constexpr int NT = COLS / 16;
    __shared__ float scN[128], shN[128];
    if (BN_IN) {
        if (threadIdx.x < 128) {
            int k = threadIdx.x;
            float invn = 1.0f / (float)NN;
            float mean = bsum[k] * invn;
            float var  = bsq[k] * invn - mean * mean;
            float sc = gamma[k] * rsqrtf(var + 1e-5f);
            scN[k] = sc;
            shN[k] = beta[k] - mean * sc;
        }
        __syncthreads();
    }
    int wv = threadIdx.x >> 6;
    int lane = threadIdx.x & 63;
    int r0 = blockIdx.x * 64 + wv * 16;
    int m = lane & 15;
    int quad = lane >> 4;
    int arow = r0 + m;
    int rc = (arow < NN) ? arow : NN - 1;    // clamp: pad rows computed but never stored
    const float* pa = A + (size_t)rc * 128 + quad * 8;

    f32x4 acc[NT];
    #pragma unroll
    for (int t = 0; t < NT; ++t) acc[t] = f32x4{0.f, 0.f, 0.f, 0.f};

    #pragma unroll
    for (int ks = 0; ks < 4; ++ks) {
        float4 v0 = *reinterpret_cast<const float4*>(pa + ks * 32);
        float4 v1 = *reinterpret_cast<const float4*>(pa + ks * 32 + 4);
        float vv[8] = {v0.x, v0.y, v0.z, v0.w, v1.x, v1.y, v1.z, v1.w};
        int kb = ks * 32 + quad * 8;
        bf16x8 ah, al;
        #pragma unroll
        for (int jj = 0; jj < 8; ++jj) {
            float f = vv[jj];
            if (BN_IN) f = fmaxf(f * scN[kb + jj] + shN[kb + jj], 0.f);
            unsigned short hi = f2bf(f);
            ah[jj] = (short)hi;
            al[jj] = (short)f2bf(f - bf2f(hi));
        }
        #pragma unroll
        for (int t = 0; t < NT; ++t) {
            size_t boff = (size_t)(t * 16 + m) * 128 + ks * 32 + quad * 8;
            bf16x8 bh = *reinterpret_cast<const bf16x8*>(Wth + boff);
            bf16x8 bl = *reinterpret_cast<const bf16x8*>(Wtl + boff);
            acc[t] = __builtin_amdgcn_mfma_f32_16x16x32_bf16(ah, bh, acc[t], 0, 0, 0);
            acc[t] = __builtin_amdgcn_mfma_f32_16x16x32_bf16(al, bh, acc[t], 0, 0, 0);
            acc[t] = __builtin_amdgcn_mfma_f32_16x16x32_bf16(ah, bl, acc[t], 0, 0, 0);
        }
    }

    // epilogue: bf16 store + fused attention dots (C/D: col=lane&15, row=quad*4+reg)
    float p[4] = {0.f, 0.f, 0.f, 0.f}, q[4] = {0.f, 0.f, 0.f, 0.f};
    #pragma unroll
    for (int t = 0; t < NT; ++t) {
        int c = t * 16 + m;
        float asv = a_src[c], adv = a_dst[c];
        #pragma unroll
        for (int rI = 0; rI < 4; ++rI) {
            float v = acc[t][rI];
            int row = r0 + quad * 4 + rI;
            if (row < NN) out[(size_t)row * COLS + c] = f2bf(v);
            p[rI] += v * asv;
            q[rI] += v * adv;
        }
    }
    #pragma unroll
    for (int rI = 0; rI < 4; ++rI) {
        #pragma unroll
        for (int off = 1; off <= 8; off <<= 1) {
            p[rI] += __shfl_xor(p[rI], off);
            q[rI] += __shfl_xor(q[rI], off);
        }
    }
    if (m == 0) {
        #pragma unroll
        for (int rI = 0; rI < 4; ++rI) {
            int row = r0 + quad * 4 + rI;
            if (row < NN) { als[row] = p[rI]; ald[row] = q[rI]; }
        }
    }
}

// ---------------- per-dst aggregate: grid-stride, quarter-wave edge split, fused BN partials --
template<int COLS, int LAYER>
__global__ void k_aggregate(const int* __restrict__ rp, const int4* __restrict__ pack,
                            const float* __restrict__ als, const float* __restrict__ ald,
                            const unsigned short* __restrict__ xs, float* __restrict__ out,
                            float* __restrict__ psum, float* __restrict__ psq)
{
    __shared__ float sS[4 * 128], sQ[4 * 128];
    int wv = threadIdx.x >> 6;
    int lane = threadIdx.x & 63;
    int q = lane >> 4;               // quarter 0..3 -> edge slot
    int ql = lane & 15;
    int col = ql * 8;
    bool act = (col < COLS);
    float bs[8] = {0.f,0.f,0.f,0.f,0.f,0.f,0.f,0.f};
    float bq[8] = {0.f,0.f,0.f,0.f,0.f,0.f,0.f,0.f};

    for (int w = blockIdx.x * 4 + wv; w < NN; w += AGG_NBLK * 4) {
        int beg = rp[w], end = rp[w + 1];
        float aldv = ald[w];
        float acc[8] = {0.f,0.f,0.f,0.f,0.f,0.f,0.f,0.f};
        float den = 0.f;
        int j = beg;
        for (; j + 8 <= end; j += 8) {
            int4 r0 = pack[j + q];
            int4 r1 = pack[j + 4 + q];
            float a0 = als[r0.x] + aldv + __int_as_float(LAYER ? r0.z : r0.y);
            float a1 = als[r1.x] + aldv + __int_as_float(LAYER ? r1.z : r1.y);
            a0 = a0 > 0.f ? a0 : 0.2f * a0;
            a1 = a1 > 0.f ? a1 : 0.2f * a1;
            float ex0 = __expf(a0), ex1 = __expf(a1);
            den += ex0 + ex1;
            if (act) {
                u16x8 u0 = *reinterpret_cast<const u16x8*>(xs + (size_t)r0.x * COLS + col);
                u16x8 u1 = *reinterpret_cast<const u16x8*>(xs + (size_t)r1.x * COLS + col);
                #pragma unroll
                for (int k = 0; k < 8; ++k)
                    acc[k] += ex0 * bf2f(u0[k]) + ex1 * bf2f(u1[k]);
            }
        }
        for (; j < end; j += 4) {
            int jj = j + q;
            if (jj < end) {
                int4 r = pack[jj];
                float a = als[r.x] + aldv + __int_as_float(LAYER ? r.z : r.y);
                a = a > 0.f ? a : 0.2f * a;
                float ex = __expf(a);
                den += ex;
                if (act) {
                    u16x8 u = *reinterpret_cast<const u16x8*>(xs + (size_t)r.x * COLS + col);
                    #pragma unroll
                    for (int k = 0; k < 8; ++k)
                        acc[k] += ex * bf2f(u[k]);
                }
            }
        }
        #pragma unroll
        for (int k = 0; k < 8; ++k) {
            acc[k] += __shfl_xor(acc[k], 16);
            acc[k] += __shfl_xor(acc[k], 32);
        }
        den += __shfl_xor(den, 16);
        den += __shfl_xor(den, 32);
        float inv = (end > beg) ? 1.f / den : 0.f;
        if (q == 0 && act) {
            float o[8];
            #pragma unroll
            for (int k = 0; k < 8; ++k) {
                o[k] = acc[k] * inv;
                bs[k] += o[k];
                bq[k] += o[k] * o[k];
            }
            float4 o0, o1;
            o0.x = o[0]; o0.y = o[1]; o0.z = o[2]; o0.w = o[3];
            o1.x = o[4]; o1.y = o[5]; o1.z = o[6]; o1.w = o[7];
            *reinterpret_cast<float4*>(out + (size_t)w * COLS + col) = o0;
            *reinterpret_cast<float4*>(out + (size_t)w * COLS + col + 4) = o1;
        }
    }
    // fold BN partials across the block's 4 waves
    if (q == 0) {
        #pragma unroll
        for (int k = 0; k < 8; ++k) {
            sS[wv * 128 + col + k] = bs[k];
            sQ[wv * 128 + col + k] = bq[k];
        }
    }
    __syncthreads();
    int t = threadIdx.x;
    if (t < 128) {
        psum[(size_t)blockIdx.x * 128 + t] = sS[t] + sS[128 + t] + sS[256 + t] + sS[384 + t];
        psq [(size_t)blockIdx.x * 128 + t] = sQ[t] + sQ[128 + t] + sQ[256 + t] + sQ[384 + t];
    }
}

// ---------------- BN stats stage 2: reduce AGG_NBLK partials (lightly-contended atomics) ----
__global__ void k_bn_stats2(const float* __restrict__ psum, const float* __restrict__ psq,
                            float* __restrict__ sums, float* __restrict__ sqs)
{
    int t = threadIdx.x;
    int c = t & 127;
    constexpr int ROWS = AGG_NBLK / 128;    // 16
    const float* sp = (t < 128) ? psum : psq;
    float s = 0.f;
    #pragma unroll 4
    for (int i = 0; i < ROWS; ++i)
        s += sp[(size_t)(blockIdx.x * ROWS + i) * 128 + c];
    unsafeAtomicAdd(((t < 128) ? sums : sqs) + c, s);
}

// ---------------- batchnorm apply (final layer -> d_out) ----------------
template<int COLS>
__global__ void k_bn_apply(const float* __restrict__ in, float* __restrict__ out,
                           const float* __restrict__ sums, const float* __restrict__ sqs,
                           const float* __restrict__ gamma, const float* __restrict__ beta,
                           int n)
{
    int idx = blockIdx.x * blockDim.x + threadIdx.x;
    if (idx >= n * COLS) return;
    int c = idx % COLS;
    float invn = 1.0f / (float)n;
    float mean = sums[c] * invn;
    float var  = sqs[c] * invn - mean * mean;     // biased, matches jnp var
    float sc = gamma[c] * rsqrtf(var + 1e-5f);
    float sh = beta[c] - mean * sc;
    out[idx] = in[idx] * sc + sh;
}

extern "C" void kernel_launch(void* const* d_in, const int* in_sizes, int n_in,
                              void* d_out, int out_size, void* d_ws, size_t ws_size,
                              hipStream_t stream)
{
    const float* x    = (const float*)d_in[0];
    const int*   eidx = (const int*)d_in[1];
    const float* eatt = (const float*)d_in[2];
    const float* W0   = (const float*)d_in[3];
    const float* as0  = (const float*)d_in[4];
    const float* ad0  = (const float*)d_in[5];
    const float* We0  = (const float*)d_in[6];
    const float* ae0  = (const float*)d_in[7];
    // d_in[8] = b0 : cancels through BN
    const float* W1   = (const float*)d_in[9];
    const float* as1  = (const float*)d_in[10];
    const float* ad1  = (const float*)d_in[11];
    const float* We1  = (const float*)d_in[12];
    const float* ae1  = (const float*)d_in[13];
    // d_in[14] = b1 : cancels through BN
    const float* bng  = (const float*)d_in[15];
    const float* bnb  = (const float*)d_in[16];
    const float* bnfg = (const float*)d_in[17];
    const float* bnfb = (const float*)d_in[18];

    const int N = NN, E = NE;
    const int* src = eidx;
    const int* dst = eidx + E;

    float* ws = (float*)d_ws;
    size_t off = 0;
    unsigned short* xs0b = (unsigned short*)(ws + off); off += (size_t)N * 64;   // N*128 bf16
    float* h   = ws + off;      off += (size_t)N * 128;                          // fp32 25.6MB
    unsigned short* xs1b = (unsigned short*)(ws + off); off += (size_t)N * 56;   // N*112 bf16
    int4*  pack = (int4*)(ws + off);    off += (size_t)E * 4;                    // 16B/edge
    int*   rp   = (int*)(ws + off);     off += N + 2;
    int*   bcur = (int*)(ws + off);     off += NBUCK;
    float* als0 = ws + off;     off += N;
    float* ald0 = ws + off;     off += N;
    float* als1 = ws + off;     off += N;
    float* ald1 = ws + off;     off += N;
    float* stats = ws + off;    off += 512;
    float* ve = ws + off;       off += 16;
    float* psum = ws + off;     off += (size_t)AGG_NBLK * 128;
    float* psq  = ws + off;     off += (size_t)AGG_NBLK * 128;
    unsigned short* Wth0 = (unsigned short*)(ws + off); off += 128 * 64;         // 128x128 bf16
    unsigned short* Wtl0 = (unsigned short*)(ws + off); off += 128 * 64;
    unsigned short* Wth1 = (unsigned short*)(ws + off); off += 112 * 64;         // 112x128 bf16
    unsigned short* Wtl1 = (unsigned short*)(ws + off); off += 112 * 64;
    int4*  bucket = (int4*)h;   // alias: NBUCK*BCAP*16B = 19.2MB <= 25.6MB; h first
                                // written by agg0, after k_sortB has consumed bucket
    float* out1 = h;            // alias: h (fp32) dead after layer-1 gemm consumes it

    float* sum0 = stats;
    float* sq0  = stats + 128;
    float* sum1 = stats + 256;
    float* sq1  = stats + 384;

    // ---- init (ws poisoned 0xAA before every call) ----
    k_init_cvt<<<(N + 255) / 256, 256, 0, stream>>>(bcur, stats, We0, ae0, We1, ae1, ve,
                                                    W0, W1, Wth0, Wtl0, Wth1, Wtl1);

    // ---- CSR build via bucket sort (replaces deg/scan/csr_fill) ----
    k_bucketA<<<(E + 255) / 256, 256, 0, stream>>>(src, dst, eatt, ve, bcur, bucket);
    k_sortB<<<NBUCK, 256, 0, stream>>>(bcur, bucket, pack, rp);

    // ---- layer 0: 128 -> 128 ----
    k_gemm_mfma<128, false><<<NPAD / 64, 256, 0, stream>>>(x, Wth0, Wtl0, xs0b,
                                                           as0, ad0, als0, ald0,
                                                           nullptr, nullptr, nullptr, nullptr);
    k_aggregate<128, 0><<<AGG_NBLK, 256, 0, stream>>>(rp, pack, als0, ald0, xs0b, h, psum, psq);
    k_bn_stats2<<<128, 256, 0, stream>>>(psum, psq, sum0, sq0);

    // ---- layer 1: 128 -> 112 (BN0+ReLU fused into GEMM A-load) ----
    k_gemm_mfma<112, true><<<NPAD / 64, 256, 0, stream>>>(h, Wth1, Wtl1, xs1b,
                                                          as1, ad1, als1, ald1,
                                                          sum0, sq0, bng, bnb);
    k_aggregate<112, 1><<<AGG_NBLK, 256, 0, stream>>>(rp, pack, als1, ald1, xs1b, out1, psum, psq);
    k_bn_stats2<<<128, 256, 0, stream>>>(psum, psq, sum1, sq1);
    k_bn_apply<112><<<(N * 112 + 255) / 256, 256, 0, stream>>>(out1, (float*)d_out, sum1, sq1, bnfg, bnfb, N);
}

// Round 11
// 397.505 us; speedup vs baseline: 1.2806x; 1.2806x over previous
//
#include <hip/hip_runtime.h>
#include <math.h>

// GAT 2-layer: N=50000 nodes, E=800000 edges, heads=1
// dims: 128 -> 128 (BN+ReLU) -> 112 (BN)
#define NN 50000
#define NPAD 50048               // 782 * 64, MFMA row tiles
#define NE 800000
#define SCAN_B 256
#define SCAN_NBLK ((NN + SCAN_B - 1) / SCAN_B)   // 196
#define AGG_NBLK 2048

typedef __attribute__((ext_vector_type(8))) short bf16x8;           // MFMA A/B frag
typedef __attribute__((ext_vector_type(4))) float f32x4;            // MFMA C/D frag
typedef __attribute__((ext_vector_type(8))) unsigned short u16x8;   // 16B gather

__device__ __forceinline__ unsigned short f2bf(float x) {
    unsigned u = __float_as_uint(x);
    u += 0x7fffu + ((u >> 16) & 1);              // round-to-nearest-even
    return (unsigned short)(u >> 16);
}
__device__ __forceinline__ float bf2f(unsigned short h) {
    return __uint_as_float(((unsigned)h) << 16);
}

// ---------------- init: deg/stats zero + ve fold + W split-transpose ----------------
// ve[0..7] = We0 @ a_edge0 ; ve[8..15] = We1 @ a_edge1   (heads=1 folding)
__global__ void k_init_cvt(int* __restrict__ deg, float* __restrict__ stats,
                           const float* __restrict__ We0, const float* __restrict__ ae0,
                           const float* __restrict__ We1, const float* __restrict__ ae1,
                           float* __restrict__ ve,
                           const float* __restrict__ W0, const float* __restrict__ W1,
                           unsigned short* __restrict__ Wth0, unsigned short* __restrict__ Wtl0,
                           unsigned short* __restrict__ Wth1, unsigned short* __restrict__ Wtl1)
{
    int idx = blockIdx.x * 256 + threadIdx.x;
    if (idx < NN) deg[idx] = 0;
    if (idx < 512) stats[idx] = 0.f;
    if (idx < 128 * 128) {
        int k = idx / 128, c = idx % 128;
        float v = W0[idx];
        unsigned short hi = f2bf(v);
        Wth0[c * 128 + k] = hi;
        Wtl0[c * 128 + k] = f2bf(v - bf2f(hi));
    } else if (idx < 128 * 128 + 128 * 112) {
        int i2 = idx - 128 * 128;
        int k = i2 / 112, c = i2 % 112;
        float v = W1[i2];
        unsigned short hi = f2bf(v);
        Wth1[c * 128 + k] = hi;
        Wtl1[c * 128 + k] = f2bf(v - bf2f(hi));
    }
    if (blockIdx.x == gridDim.x - 1) {
        int j = threadIdx.x;
        if (j < 8) {
            float s = 0.f;
            for (int c = 0; c < 128; ++c) s += We0[j * 128 + c] * ae0[c];
            ve[j] = s;
        } else if (j < 16) {
            int jj = j - 8;
            float s = 0.f;
            for (int c = 0; c < 112; ++c) s += We1[jj * 112 + c] * ae1[c];
            ve[8 + jj] = s;
        }
    }
}

// ---------------- CSR build ----------------
__global__ void k_deg(const int* __restrict__ dst, int* __restrict__ deg, int E_)
{
    int e = blockIdx.x * blockDim.x + threadIdx.x;
    if (e < E_) atomicAdd(&deg[dst[e]], 1);
}

__global__ void k_scan1(const int* __restrict__ deg, int* __restrict__ partial)
{
    __shared__ int sm[SCAN_B];
    int t = threadIdx.x;
    int idx = blockIdx.x * SCAN_B + t;
    sm[t] = (idx < NN) ? deg[idx] : 0;
    __syncthreads();
    #pragma unroll
    for (int off = SCAN_B / 2; off > 0; off >>= 1) {
        if (t < off) sm[t] += sm[t + off];
        __syncthreads();
    }
    if (t == 0) partial[blockIdx.x] = sm[0];
}

// fused stage 2+3: each block computes its own prefix over partials, then local scan
__global__ void k_scan3(const int* __restrict__ deg, const int* __restrict__ partial,
                        int* __restrict__ rp, int* __restrict__ cur)
{
    __shared__ int sm[SCAN_B];
    __shared__ int pbase;
    int t = threadIdx.x;
    int pv = (t < SCAN_NBLK && t < blockIdx.x) ? partial[t] : 0;
    sm[t] = pv;
    __syncthreads();
    #pragma unroll
    for (int off = SCAN_B / 2; off > 0; off >>= 1) {
        if (t < off) sm[t] += sm[t + off];
        __syncthreads();
    }
    if (t == 0) pbase = sm[0];
    __syncthreads();
    int idx = blockIdx.x * SCAN_B + t;
    int v = (idx < NN) ? deg[idx] : 0;
    sm[t] = v;
    __syncthreads();
    #pragma unroll
    for (int off = 1; off < SCAN_B; off <<= 1) {
        int u = (t >= off) ? sm[t - off] : 0;
        __syncthreads();
        sm[t] += u;
        __syncthreads();
    }
    int excl = pbase + ((t == 0) ? 0 : sm[t - 1]);
    if (idx < NN) { rp[idx] = excl; cur[idx] = excl; }
    if (idx == NN - 1) rp[NN] = excl + v;
}

// ---------------- edge pack: 8B records {src, bf16 a0 | bf16 a1<<16}, CSR order ----------------
__global__ void k_csr_fill(const int* __restrict__ src, const int* __restrict__ dst,
                           const float* __restrict__ eatt, const float* __restrict__ ve,
                           int* __restrict__ cur, uint2* __restrict__ pack, int E_)
{
    int e = blockIdx.x * blockDim.x + threadIdx.x;
    if (e >= E_) return;
    const float4* ea = reinterpret_cast<const float4*>(eatt + (size_t)e * 8);
    float4 e0 = ea[0], e1 = ea[1];
    float a0 = e0.x * ve[0] + e0.y * ve[1] + e0.z * ve[2] + e0.w * ve[3]
             + e1.x * ve[4] + e1.y * ve[5] + e1.z * ve[6] + e1.w * ve[7];
    float a1 = e0.x * ve[8] + e0.y * ve[9] + e0.z * ve[10] + e0.w * ve[11]
             + e1.x * ve[12] + e1.y * ve[13] + e1.z * ve[14] + e1.w * ve[15];
    int d = dst[e];
    int pos = atomicAdd(&cur[d], 1);
    uint2 rec;
    rec.x = (unsigned)src[e];
    rec.y = (unsigned)f2bf(a0) | ((unsigned)f2bf(a1) << 16);
    pack[pos] = rec;
}

// ---------------- MFMA GEMM: one wave = 16 rows x COLS, bf16x3 split precision ----------------
template<int COLS, bool BN_IN>
__global__ void k_gemm_mfma(const float* __restrict__ A,
                            const unsigned short* __restrict__ Wth,
                            const unsigned short* __restrict__ Wtl,
                            unsigned short* __restrict__ out,
                            const float* __restrict__ a_src, const float* __restrict__ a_dst,
                            float* __restrict__ als, float* __restrict__ ald,
                            const float* __restrict__ bsum, const float* __restrict__ bsq,
                            const float* __restrict__ gamma, const float* __restrict__ beta)
{
    constexpr int NT = COLS / 16;
    __shared__ float scN[128], shN[128];
    if (BN_IN) {
        if (threadIdx.x < 128) {
            int k = threadIdx.x;
            float invn = 1.0f / (float)NN;
            float mean = bsum[k] * invn;
            float var  = bsq[k] * invn - mean * mean;
            float sc = gamma[k] * rsqrtf(var + 1e-5f);
            scN[k] = sc;
            shN[k] = beta[k] - mean * sc;
        }
        __syncthreads();
    }
    int wv = threadIdx.x >> 6;
    int lane = threadIdx.x & 63;
    int r0 = blockIdx.x * 64 + wv * 16;
    int m = lane & 15;
    int quad = lane >> 4;
    int arow = r0 + m;
    int rc = (arow < NN) ? arow : NN - 1;    // clamp: pad rows computed but never stored
    const float* pa = A + (size_t)rc * 128 + quad * 8;

    f32x4 acc[NT];
    #pragma unroll
    for (int t = 0; t < NT; ++t) acc[t] = f32x4{0.f, 0.f, 0.f, 0.f};

    #pragma unroll
    for (int ks = 0; ks < 4; ++ks) {
        float4 v0 = *reinterpret_cast<const float4*>(pa + ks * 32);
        float4 v1 = *reinterpret_cast<const float4*>(pa + ks * 32 + 4);
        float vv[8] = {v0.x, v0.y, v0.z, v0.w, v1.x, v1.y, v1.z, v1.w};
        int kb = ks * 32 + quad * 8;
        bf16x8 ah, al;
        #pragma unroll
        for (int jj = 0; jj < 8; ++jj) {
            float f = vv[jj];
            if (BN_IN) f = fmaxf(f * scN[kb + jj] + shN[kb + jj], 0.f);
            unsigned short hi = f2bf(f);
            ah[jj] = (short)hi;
            al[jj] = (short)f2bf(f - bf2f(hi));
        }
        #pragma unroll
        for (int t = 0; t < NT; ++t) {
            size_t boff = (size_t)(t * 16 + m) * 128 + ks * 32 + quad * 8;
            bf16x8 bh = *reinterpret_cast<const bf16x8*>(Wth + boff);
            bf16x8 bl = *reinterpret_cast<const bf16x8*>(Wtl + boff);
            acc[t] = __builtin_amdgcn_mfma_f32_16x16x32_bf16(ah, bh, acc[t], 0, 0, 0);
            acc[t] = __builtin_amdgcn_mfma_f32_16x16x32_bf16(al, bh, acc[t], 0, 0, 0);
            acc[t] = __builtin_amdgcn_mfma_f32_16x16x32_bf16(ah, bl, acc[t], 0, 0, 0);
        }
    }

    // epilogue: bf16 store + fused attention dots (C/D: col=lane&15, row=quad*4+reg)
    float p[4] = {0.f, 0.f, 0.f, 0.f}, q[4] = {0.f, 0.f, 0.f, 0.f};
    #pragma unroll
    for (int t = 0; t < NT; ++t) {
        int c = t * 16 + m;
        float asv = a_src[c], adv = a_dst[c];
        #pragma unroll
        for (int rI = 0; rI < 4; ++rI) {
            float v = acc[t][rI];
            int row = r0 + quad * 4 + rI;
            if (row < NN) out[(size_t)row * COLS + c] = f2bf(v);
            p[rI] += v * asv;
            q[rI] += v * adv;
        }
    }
    #pragma unroll
    for (int rI = 0; rI < 4; ++rI) {
        #pragma unroll
        for (int off = 1; off <= 8; off <<= 1) {
            p[rI] += __shfl_xor(p[rI], off);
            q[rI] += __shfl_xor(q[rI], off);
        }
    }
    if (m == 0) {
        #pragma unroll
        for (int rI = 0; rI < 4; ++rI) {
            int row = r0 + quad * 4 + rI;
            if (row < NN) { als[row] = p[rI]; ald[row] = q[rI]; }
        }
    }
}

// ---------------- per-dst aggregate: grid-stride, quarter-wave edge split, fused BN partials --
// 16 lanes per edge, u16x8 (16B) per lane; 4 edges/pass, unroll x2 -> 8 gathers in flight.
template<int COLS, int LAYER>
__global__ void k_aggregate(const int* __restrict__ rp, const uint2* __restrict__ pack,
                            const float* __restrict__ als, const float* __restrict__ ald,
                            const unsigned short* __restrict__ xs, float* __restrict__ out,
                            float* __restrict__ psum, float* __restrict__ psq)
{
    __shared__ float sS[4 * 128], sQ[4 * 128];
    int wv = threadIdx.x >> 6;
    int lane = threadIdx.x & 63;
    int q = lane >> 4;               // quarter 0..3 -> edge slot
    int ql = lane & 15;
    int col = ql * 8;
    bool act = (col < COLS);
    float bs[8] = {0.f,0.f,0.f,0.f,0.f,0.f,0.f,0.f};
    float bq[8] = {0.f,0.f,0.f,0.f,0.f,0.f,0.f,0.f};

    for (int w = blockIdx.x * 4 + wv; w < NN; w += AGG_NBLK * 4) {
        int beg = rp[w], end = rp[w + 1];
        float aldv = ald[w];
        float acc[8] = {0.f,0.f,0.f,0.f,0.f,0.f,0.f,0.f};
        float den = 0.f;
        int j = beg;
        for (; j + 8 <= end; j += 8) {
            uint2 r0 = pack[j + q];
            uint2 r1 = pack[j + 4 + q];
            float a0 = als[r0.x] + aldv
                     + bf2f((unsigned short)(LAYER ? (r0.y >> 16) : (r0.y & 0xffffu)));
            float a1 = als[r1.x] + aldv
                     + bf2f((unsigned short)(LAYER ? (r1.y >> 16) : (r1.y & 0xffffu)));
            a0 = a0 > 0.f ? a0 : 0.2f * a0;
            a1 = a1 > 0.f ? a1 : 0.2f * a1;
            float ex0 = __expf(a0), ex1 = __expf(a1);
            den += ex0 + ex1;
            if (act) {
                u16x8 u0 = *reinterpret_cast<const u16x8*>(xs + (size_t)r0.x * COLS + col);
                u16x8 u1 = *reinterpret_cast<const u16x8*>(xs + (size_t)r1.x * COLS + col);
                #pragma unroll
                for (int k = 0; k < 8; ++k)
                    acc[k] += ex0 * bf2f(u0[k]) + ex1 * bf2f(u1[k]);
            }
        }
        for (; j < end; j += 4) {
            int jj = j + q;
            if (jj < end) {
                uint2 r = pack[jj];
                float a = als[r.x] + aldv
                        + bf2f((unsigned short)(LAYER ? (r.y >> 16) : (r.y & 0xffffu)));
                a = a > 0.f ? a : 0.2f * a;
                float ex = __expf(a);
                den += ex;
                if (act) {
                    u16x8 u = *reinterpret_cast<const u16x8*>(xs + (size_t)r.x * COLS + col);
                    #pragma unroll
                    for (int k = 0; k < 8; ++k)
                        acc[k] += ex * bf2f(u[k]);
                }
            }
        }
        #pragma unroll
        for (int k = 0; k < 8; ++k) {
            acc[k] += __shfl_xor(acc[k], 16);
            acc[k] += __shfl_xor(acc[k], 32);
        }
        den += __shfl_xor(den, 16);
        den += __shfl_xor(den, 32);
        float inv = (end > beg) ? 1.f / den : 0.f;
        if (q == 0 && act) {
            float o[8];
            #pragma unroll
            for (int k = 0; k < 8; ++k) {
                o[k] = acc[k] * inv;
                bs[k] += o[k];
                bq[k] += o[k] * o[k];
            }
            float4 o0, o1;
            o0.x = o[0]; o0.y = o[1]; o0.z = o[2]; o0.w = o[3];
            o1.x = o[4]; o1.y = o[5]; o1.z = o[6]; o1.w = o[7];
            *reinterpret_cast<float4*>(out + (size_t)w * COLS + col) = o0;
            *reinterpret_cast<float4*>(out + (size_t)w * COLS + col + 4) = o1;
        }
    }
    // fold BN partials across the block's 4 waves
    if (q == 0) {
        #pragma unroll
        for (int k = 0; k < 8; ++k) {
            sS[wv * 128 + col + k] = bs[k];
            sQ[wv * 128 + col + k] = bq[k];
        }
    }
    __syncthreads();
    int t = threadIdx.x;
    if (t < 128) {
        psum[(size_t)blockIdx.x * 128 + t] = sS[t] + sS[128 + t] + sS[256 + t] + sS[384 + t];
        psq [(size_t)blockIdx.x * 128 + t] = sQ[t] + sQ[128 + t] + sQ[256 + t] + sQ[384 + t];
    }
}

// ---------------- BN stats stage 2: reduce AGG_NBLK partials (lightly-contended atomics) ----
__global__ void k_bn_stats2(const float* __restrict__ psum, const float* __restrict__ psq,
                            float* __restrict__ sums, float* __restrict__ sqs)
{
    int t = threadIdx.x;
    int c = t & 127;
    constexpr int ROWS = AGG_NBLK / 128;    // 16
    const float* sp = (t < 128) ? psum : psq;
    float s = 0.f;
    #pragma unroll 4
    for (int i = 0; i < ROWS; ++i)
        s += sp[(size_t)(blockIdx.x * ROWS + i) * 128 + c];
    unsafeAtomicAdd(((t < 128) ? sums : sqs) + c, s);
}

// ---------------- batchnorm apply (final layer -> d_out) ----------------
template<int COLS>
__global__ void k_bn_apply(const float* __restrict__ in, float* __restrict__ out,
                           const float* __restrict__ sums, const float* __restrict__ sqs,
                           const float* __restrict__ gamma, const float* __restrict__ beta,
                           int n)
{
    int idx = blockIdx.x * blockDim.x + threadIdx.x;
    if (idx >= n * COLS) return;
    int c = idx % COLS;
    float invn = 1.0f / (float)n;
    float mean = sums[c] * invn;
    float var  = sqs[c] * invn - mean * mean;     // biased, matches jnp var
    float sc = gamma[c] * rsqrtf(var + 1e-5f);
    float sh = beta[c] - mean * sc;
    out[idx] = in[idx] * sc + sh;
}

extern "C" void kernel_launch(void* const* d_in, const int* in_sizes, int n_in,
                              void* d_out, int out_size, void* d_ws, size_t ws_size,
                              hipStream_t stream)
{
    const float* x    = (const float*)d_in[0];
    const int*   eidx = (const int*)d_in[1];
    const float* eatt = (const float*)d_in[2];
    const float* W0   = (const float*)d_in[3];
    const float* as0  = (const float*)d_in[4];
    const float* ad0  = (const float*)d_in[5];
    const float* We0  = (const float*)d_in[6];
    const float* ae0  = (const float*)d_in[7];
    // d_in[8] = b0 : cancels through BN
    const float* W1   = (const float*)d_in[9];
    const float* as1  = (const float*)d_in[10];
    const float* ad1  = (const float*)d_in[11];
    const float* We1  = (const float*)d_in[12];
    const float* ae1  = (const float*)d_in[13];
    // d_in[14] = b1 : cancels through BN
    const float* bng  = (const float*)d_in[15];
    const float* bnb  = (const float*)d_in[16];
    const float* bnfg = (const float*)d_in[17];
    const float* bnfb = (const float*)d_in[18];

    const int N = NN, E = NE;
    const int* src = eidx;
    const int* dst = eidx + E;

    float* ws = (float*)d_ws;
    size_t off = 0;
    unsigned short* xs0b = (unsigned short*)(ws + off); off += (size_t)N * 64;   // N*128 bf16
    float* h   = ws + off;      off += (size_t)N * 128;                          // fp32 25.6MB
    unsigned short* xs1b = (unsigned short*)(ws + off); off += (size_t)N * 56;   // N*112 bf16
    uint2* pack = (uint2*)(ws + off);   off += (size_t)E * 2;                    // 8B/edge
    int*   rp   = (int*)(ws + off);     off += N + 2;
    int*   cur  = (int*)(ws + off);     off += N;
    int*   deg  = (int*)(ws + off);     off += N;
    float* als0 = ws + off;     off += N;
    float* ald0 = ws + off;     off += N;
    float* als1 = ws + off;     off += N;
    float* ald1 = ws + off;     off += N;
    float* stats = ws + off;    off += 512;
    float* ve = ws + off;       off += 16;
    int*   partial = (int*)(ws + off);  off += SCAN_NBLK;
    float* psum = ws + off;     off += (size_t)AGG_NBLK * 128;
    float* psq  = ws + off;     off += (size_t)AGG_NBLK * 128;
    unsigned short* Wth0 = (unsigned short*)(ws + off); off += 128 * 64;         // 128x128 bf16
    unsigned short* Wtl0 = (unsigned short*)(ws + off); off += 128 * 64;
    unsigned short* Wth1 = (unsigned short*)(ws + off); off += 112 * 64;         // 112x128 bf16
    unsigned short* Wtl1 = (unsigned short*)(ws + off); off += 112 * 64;
    float* out1 = h;            // alias: h (fp32) dead after layer-1 gemm consumes it

    float* sum0 = stats;
    float* sq0  = stats + 128;
    float* sum1 = stats + 256;
    float* sq1  = stats + 384;

    // ---- init (ws poisoned 0xAA before every call) ----
    k_init_cvt<<<(N + 255) / 256, 256, 0, stream>>>(deg, stats, We0, ae0, We1, ae1, ve,
                                                    W0, W1, Wth0, Wtl0, Wth1, Wtl1);

    // ---- CSR build: deg -> scan -> direct fill (50K cursors: no hot-counter chains) ----
    k_deg<<<(E + 255) / 256, 256, 0, stream>>>(dst, deg, E);
    k_scan1<<<SCAN_NBLK, SCAN_B, 0, stream>>>(deg, partial);
    k_scan3<<<SCAN_NBLK, SCAN_B, 0, stream>>>(deg, partial, rp, cur);
    k_csr_fill<<<(E + 255) / 256, 256, 0, stream>>>(src, dst, eatt, ve, cur, pack, E);

    // ---- layer 0: 128 -> 128 ----
    k_gemm_mfma<128, false><<<NPAD / 64, 256, 0, stream>>>(x, Wth0, Wtl0, xs0b,
                                                           as0, ad0, als0, ald0,
                                                           nullptr, nullptr, nullptr, nullptr);
    k_aggregate<128, 0><<<AGG_NBLK, 256, 0, stream>>>(rp, pack, als0, ald0, xs0b, h, psum, psq);
    k_bn_stats2<<<128, 256, 0, stream>>>(psum, psq, sum0, sq0);

    // ---- layer 1: 128 -> 112 (BN0+ReLU fused into GEMM A-load) ----
    k_gemm_mfma<112, true><<<NPAD / 64, 256, 0, stream>>>(h, Wth1, Wtl1, xs1b,
                                                          as1, ad1, als1, ald1,
                                                          sum0, sq0, bng, bnb);
    k_aggregate<112, 1><<<AGG_NBLK, 256, 0, stream>>>(rp, pack, als1, ald1, xs1b, out1, psum, psq);
    k_bn_stats2<<<128, 256, 0, stream>>>(psum, psq, sum1, sq1);
    k_bn_apply<112><<<(N * 112 + 255) / 256, 256, 0, stream>>>(out1, (float*)d_out, sum1, sq1, bnfg, bnfb, N);
}